// Round 5
// baseline (159.771 us; speedup 1.0000x reference)
//
#include <hip/hip_runtime.h>
#include <hip/hip_bf16.h>

// MechanismGrabber: B=2,S=4096,D=128,M=64. Outputs: integrated [8192,128] f32, vp [8192] f32.
// R5: fused kernel now 512 threads/block (8 waves = 2 row-halves x 4 e-quarters) -> 2 waves/SIMD,
// grid stays 256 (1 block/CU, Wt^T L2 traffic unchanged). Phase B barrier-free depth-3 L2 pipeline.

typedef __bf16 bf16_t;
typedef __bf16 bf16x8 __attribute__((ext_vector_type(8)));
typedef float  f32x4  __attribute__((ext_vector_type(4)));

// ws layout (bytes)
#define WS_WTT      0u          // bf16 [m][ks(4)][e(128)][g(4)][j(8)]  (frag-major Wt^T), 2 MB
#define WS_W1T      2097152u    // bf16 [256 out][256 in]
#define WS_W2T      2228224u    // bf16 [64 out][256 in]
#define WS_OT       2260992u    // bf16 [64 out][64 in]
#define WS_WG       2269184u    // bf16 [64][128]
#define WS_U        2285568u    // bf16 [64][128]
#define WS_CVEC     2301952u    // f32  [64]
#define WS_BCT      2302208u    // bf16 [128 e][64 m]  (bt+char)^T
#define WS_WIT      2318592u    // bf16 [128 out][256 in]

#define VP_OFF 1048576

__device__ __forceinline__ f32x4 mfma16(bf16x8 a, bf16x8 b, f32x4 c) {
  return __builtin_amdgcn_mfma_f32_16x16x32_bf16(a, b, c, 0, 0, 0);
}

__device__ __forceinline__ float gelu_exact(float v) {
  return 0.5f * v * (1.0f + erff(v * 0.70710678118654752f));
}
__device__ __forceinline__ float sigmoidf_(float v) {
  return 1.0f / (1.0f + __expf(-v));
}

__device__ __forceinline__ bf16x8 cvt8(float4 v0, float4 v1) {
  bf16x8 a;
  a[0] = (bf16_t)v0.x; a[1] = (bf16_t)v0.y; a[2] = (bf16_t)v0.z; a[3] = (bf16_t)v0.w;
  a[4] = (bf16_t)v1.x; a[5] = (bf16_t)v1.y; a[6] = (bf16_t)v1.z; a[7] = (bf16_t)v1.w;
  return a;
}

// ---------------------------------------------------------------- kernel P
__global__ __launch_bounds__(256) void kprep(
    const float* __restrict__ Wt, const float* __restrict__ bt,
    const float* __restrict__ ch, const float* __restrict__ Wg,
    const float* __restrict__ Wv, const float* __restrict__ bv,
    const float* __restrict__ O, const float* __restrict__ W1,
    const float* __restrict__ W2, const float* __restrict__ Wi,
    char* __restrict__ ws)
{
  const int bid = blockIdx.x, tid = threadIdx.x;
  if (bid < 128) {
    // Wt[m][d][e] -> Wtt[m][ks][e][g][j] bf16 (d = ks*32+g*8+j); 2 blocks per m.
    const int m = bid >> 1, half = bid & 1;
    const float* wtm = Wt + m * 16384;
    bf16_t* wtt = (bf16_t*)(ws + WS_WTT) + m * 16384;
    const int ks = half * 2 + (tid >> 7), e = tid & 127;
    bf16_t tmp[32];
    #pragma unroll
    for (int dd = 0; dd < 32; ++dd)
      tmp[dd] = (bf16_t)wtm[(ks * 32 + dd) * 128 + e];
    bf16_t* dst = wtt + ks * 4096 + e * 32;
    #pragma unroll
    for (int g = 0; g < 4; ++g)
      *(bf16x8*)(dst + g * 8) = *(const bf16x8*)(tmp + g * 8);
  } else if (bid < 144) {  // W1t[c][k] = W1[k][c]
    int base = (bid - 128) * 256 + tid;
    int k = base >> 4, c0 = (base & 15) * 16;
    bf16_t* o = (bf16_t*)(ws + WS_W1T);
    #pragma unroll
    for (int j = 0; j < 16; ++j) o[(c0 + j) * 256 + k] = (bf16_t)W1[k * 256 + c0 + j];
  } else if (bid < 146) {  // W2t
    int base = (bid - 144) * 256 + tid;
    int k = base >> 1, c0 = (base & 1) * 32;
    bf16_t* o = (bf16_t*)(ws + WS_W2T);
    #pragma unroll
    for (int j = 0; j < 32; ++j) o[(c0 + j) * 256 + k] = (bf16_t)W2[k * 64 + c0 + j];
  } else if (bid == 146) { // Ot
    int k = tid >> 2, c0 = (tid & 3) * 16;
    bf16_t* o = (bf16_t*)(ws + WS_OT);
    #pragma unroll
    for (int j = 0; j < 16; ++j) o[(c0 + j) * 64 + k] = (bf16_t)O[k * 64 + c0 + j];
  } else if (bid == 147) { // Wg bf16 copy
    bf16_t* o = (bf16_t*)(ws + WS_WG);
    #pragma unroll
    for (int j = 0; j < 32; ++j) o[tid * 32 + j] = (bf16_t)Wg[tid * 32 + j];
  } else if (bid == 148) { // bct[e][m]
    bf16_t* o = (bf16_t*)(ws + WS_BCT);
    #pragma unroll
    for (int i = 0; i < 4; ++i) {
      int task = tid + i * 256;
      int m = task >> 4, e0 = (task & 15) * 8;
      #pragma unroll
      for (int j = 0; j < 8; ++j)
        o[(e0 + j) * 64 + m] = (bf16_t)(bt[m * 128 + e0 + j] + ch[m * 128 + e0 + j]);
    }
  } else if (bid < 153) {  // 149..152: Wit
    int base = (bid - 149) * 256 + tid;
    int k = base >> 2, c0 = (base & 3) * 32;
    bf16_t* o = (bf16_t*)(ws + WS_WIT);
    #pragma unroll
    for (int j = 0; j < 32; ++j) o[(c0 + j) * 256 + k] = (bf16_t)Wi[k * 128 + c0 + j];
  } else if (bid < 185) {  // 153..184: u[m][d] = Wt[m][d][:] . Wv[m][:], vectorized
    int task = (bid - 153) * 256 + tid;   // 8192 tasks
    int m = task >> 7, d = task & 127;
    const float4* wp = (const float4*)(Wt + m * 16384 + d * 128);
    const float4* vp = (const float4*)(Wv + m * 128);
    float s = 0.f;
    #pragma unroll
    for (int i = 0; i < 32; ++i) {
      float4 a = wp[i], b = vp[i];
      s += a.x * b.x + a.y * b.y + a.z * b.z + a.w * b.w;
    }
    ((bf16_t*)(ws + WS_U))[m * 128 + d] = (bf16_t)s;
  } else {                 // 185: cvec
    if (tid < 64) {
      int m = tid;
      const float4* bp = (const float4*)(bt + m * 128);
      const float4* cp = (const float4*)(ch + m * 128);
      const float4* vp = (const float4*)(Wv + m * 128);
      float s = bv[m];
      #pragma unroll
      for (int i = 0; i < 32; ++i) {
        float4 a = bp[i], c = cp[i], b = vp[i];
        s += (a.x + c.x) * b.x + (a.y + c.y) * b.y + (a.z + c.z) * b.z + (a.w + c.w) * b.w;
      }
      ((float*)(ws + WS_CVEC))[m] = s;
    }
  }
}

// ---------------------------------------------------------------- fused kernel
__device__ __forceinline__ void loadF(bf16x8 (&F)[4], const char* bbase, int m) {
  const char* p = bbase + m * 32768;
  F[0] = *(const bf16x8*)(p);
  F[1] = *(const bf16x8*)(p + 8192);
  F[2] = *(const bf16x8*)(p + 16384);
  F[3] = *(const bf16x8*)(p + 24576);
}

template<int J>
__device__ __forceinline__ void computeT(const bf16x8 (&F)[4], const f32x4 (&wc)[8],
                                         const bf16x8 (&aX)[2][4], f32x4 (&acc)[2]) {
  #pragma unroll
  for (int rg = 0; rg < 2; ++rg) {
    f32x4 y = {0.f, 0.f, 0.f, 0.f};
    #pragma unroll
    for (int ks = 0; ks < 4; ++ks) y = mfma16(aX[rg][ks], F[ks], y);
    #pragma unroll
    for (int jj = 0; jj < 4; ++jj)
      acc[rg][jj] += wc[rg * 4 + jj][J] * y[jj];
  }
}

__global__ __launch_bounds__(512, 2) void kfused(
    const float* __restrict__ x, const float* __restrict__ ctx,
    const float* __restrict__ b1, const float* __restrict__ b2,
    const float* __restrict__ bg, const float* __restrict__ bi,
    char* __restrict__ ws, float* __restrict__ out)
{
  __shared__ char sm[92160];
  bf16_t* hL      = (bf16_t*)sm;               // [64][256] bf16 swz, 32 KB
  float*  scoresL = (float*)(sm + 32768);      // [64][64]  f32, 16 KB
  float*  wL      = (float*)(sm + 49152);      // [64][68]  f32 padded, 17.4 KB
  bf16_t* scbL    = (bf16_t*)(sm + 66560);     // [64][64]  bf16 swz, 8 KB
  bf16_t* wbL     = (bf16_t*)(sm + 74752);     // [64][64]  bf16 swz, 8 KB
  bf16_t* selL    = (bf16_t*)(sm + 82944);     // [64][64]  bf16 swz, 8 KB
  float*  vpL     = (float*)(sm + 91136);      // [64][4]

  const int tid = threadIdx.x;
  const int lane = tid & 63, wid = tid >> 6;    // 8 waves
  const int rh = wid >> 2;                      // row half: rows rh*32..rh*32+31
  const int wq = wid & 3;                       // e/mech quarter
  const int tb = (blockIdx.x >> 1) * 64;
  const int eh = blockIdx.x & 1;
  const int lr = lane & 15;
  const int lg = lane >> 4;
  const int lk = lg * 8;
  const int lj4 = lg * 4;
  const int wr = rh * 32;                       // wave row base (local)

  const bf16_t* W1t = (const bf16_t*)(ws + WS_W1T);
  const bf16_t* W2t = (const bf16_t*)(ws + WS_W2T);
  const bf16_t* Ot  = (const bf16_t*)(ws + WS_OT);
  const bf16_t* Wgb = (const bf16_t*)(ws + WS_WG);
  const bf16_t* Ub  = (const bf16_t*)(ws + WS_U);
  const float*  cv  = (const float*)(ws + WS_CVEC);
  const bf16_t* bct = (const bf16_t*)(ws + WS_BCT);
  const bf16_t* Wit = (const bf16_t*)(ws + WS_WIT);
  const char*  wttc = (const char*)(ws + WS_WTT);

  // x A-frags for this wave's 32 rows (persistent: GEMM1, timing/victory, phase B, phase C)
  bf16x8 aX[2][4];
  #pragma unroll
  for (int rg = 0; rg < 2; ++rg) {
    const float* xr = x + (tb + wr + rg * 16 + lr) * 128;
    #pragma unroll
    for (int ks = 0; ks < 4; ++ks)
      aX[rg][ks] = cvt8(*(const float4*)(xr + ks * 32 + lk),
                        *(const float4*)(xr + ks * 32 + lk + 4));
  }

  // ---------------- GEMM1: [32,256]@W1 -> gelu -> hL  (wave: 32 rows x 64 cols, ks-outer)
  {
    f32x4 a1[4][2] = {{{0,0,0,0},{0,0,0,0}},{{0,0,0,0},{0,0,0,0}},
                      {{0,0,0,0},{0,0,0,0}},{{0,0,0,0},{0,0,0,0}}};
    #pragma unroll
    for (int ks = 0; ks < 8; ++ks) {
      bf16x8 af[2];
      if (ks < 4) {
        af[0] = aX[0][ks]; af[1] = aX[1][ks];
      } else {
        #pragma unroll
        for (int rg = 0; rg < 2; ++rg) {
          const float* cr = ctx + (tb + wr + rg * 16 + lr) * 128 + (ks - 4) * 32 + lk;
          af[rg] = cvt8(*(const float4*)cr, *(const float4*)(cr + 4));
        }
      }
      #pragma unroll
      for (int cg = 0; cg < 4; ++cg) {
        bf16x8 b = *(const bf16x8*)(W1t + (wq * 64 + cg * 16 + lr) * 256 + ks * 32 + lk);
        a1[cg][0] = mfma16(af[0], b, a1[cg][0]);
        a1[cg][1] = mfma16(af[1], b, a1[cg][1]);
      }
    }
    #pragma unroll
    for (int cg = 0; cg < 4; ++cg) {
      int c = wq * 64 + cg * 16 + lr;
      float bb = b1[c];
      #pragma unroll
      for (int rg = 0; rg < 2; ++rg)
        #pragma unroll
        for (int j = 0; j < 4; ++j) {
          int r = wr + rg * 16 + lj4 + j;
          float v = gelu_exact(a1[cg][rg][j] + bb);
          *(bf16_t*)((char*)hL + ((r * 512 + c * 2) ^ ((r & 7) << 4))) = (bf16_t)v;
        }
    }
  }
  __syncthreads();

  // ---------------- GEMM2: h@W2 + b2 -> logits  (wave: 32 rows x 16 mechs)
  {
    int c = wq * 16 + lr;
    f32x4 l[2] = {{0,0,0,0},{0,0,0,0}};
    #pragma unroll
    for (int ks = 0; ks < 8; ++ks) {
      int k0 = ks * 32 + lk;
      bf16x8 b = *(const bf16x8*)(W2t + c * 256 + k0);
      #pragma unroll
      for (int rg = 0; rg < 2; ++rg) {
        int r = wr + rg * 16 + lr;
        bf16x8 a = *(const bf16x8*)((char*)hL + ((r * 512 + k0 * 2) ^ ((r & 7) << 4)));
        l[rg] = mfma16(a, b, l[rg]);
      }
    }
    float bb = b2[c];
    #pragma unroll
    for (int rg = 0; rg < 2; ++rg)
      #pragma unroll
      for (int j = 0; j < 4; ++j)
        scoresL[(wr + rg * 16 + lj4 + j) * 64 + c] = l[rg][j] + bb;
  }
  __syncthreads();

  // ---------------- softmax over 64 mechs (8 threads/row x 8 vals)
  {
    int row = tid >> 3, i = tid & 7;
    float v[8];
    #pragma unroll
    for (int j = 0; j < 8; ++j) v[j] = scoresL[row * 64 + i * 8 + j];
    float mx = v[0];
    #pragma unroll
    for (int j = 1; j < 8; ++j) mx = fmaxf(mx, v[j]);
    mx = fmaxf(mx, __shfl_xor(mx, 1));
    mx = fmaxf(mx, __shfl_xor(mx, 2));
    mx = fmaxf(mx, __shfl_xor(mx, 4));
    float sum = 0.f;
    #pragma unroll
    for (int j = 0; j < 8; ++j) { v[j] = __expf(v[j] - mx); sum += v[j]; }
    sum += __shfl_xor(sum, 1);
    sum += __shfl_xor(sum, 2);
    sum += __shfl_xor(sum, 4);
    float inv = 1.0f / sum;
    #pragma unroll
    for (int j = 0; j < 8; ++j) {
      float s = v[j] * inv;
      int cc = i * 8 + j;
      scoresL[row * 64 + cc] = s;
      *(bf16_t*)((char*)scbL + ((row * 128 + cc * 2) ^ ((row & 7) << 4))) = (bf16_t)s;
    }
  }
  __syncthreads();

  // ---------------- gates / timing / victory / w  (wave: 32 rows x 16 mechs)
  {
    const int c = wq * 16 + lr;
    f32x4 g[2] = {{0,0,0,0},{0,0,0,0}};
    #pragma unroll
    for (int ks = 0; ks < 2; ++ks) {
      int k0 = ks * 32 + lk;
      bf16x8 b = *(const bf16x8*)(Ot + c * 64 + k0);
      #pragma unroll
      for (int rg = 0; rg < 2; ++rg) {
        int r = wr + rg * 16 + lr;
        bf16x8 a = *(const bf16x8*)((char*)scbL + ((r * 128 + k0 * 2) ^ ((r & 7) << 4)));
        g[rg] = mfma16(a, b, g[rg]);
      }
    }
    f32x4 t[2] = {{0,0,0,0},{0,0,0,0}};
    f32x4 v[2] = {{0,0,0,0},{0,0,0,0}};
    #pragma unroll
    for (int ks = 0; ks < 4; ++ks) {
      bf16x8 bT = *(const bf16x8*)(Wgb + c * 128 + ks * 32 + lk);
      bf16x8 bV = *(const bf16x8*)(Ub  + c * 128 + ks * 32 + lk);
      #pragma unroll
      for (int rg = 0; rg < 2; ++rg) {
        t[rg] = mfma16(aX[rg][ks], bT, t[rg]);
        v[rg] = mfma16(aX[rg][ks], bV, v[rg]);
      }
    }
    float bgc = bg[c], cvc = cv[c];
    #pragma unroll
    for (int rg = 0; rg < 2; ++rg)
      #pragma unroll
      for (int j = 0; j < 4; ++j) {
        int r = wr + rg * 16 + lj4 + j;
        float gate = 1.0f + tanhf(g[rg][j]);
        float tim  = sigmoidf_(t[rg][j] + bgc);
        float vic  = sigmoidf_(v[rg][j] + cvc);
        float sc   = scoresL[r * 64 + c];
        float w    = gate * sc * tim;
        wL[r * 68 + c] = w;
        *(bf16_t*)((char*)wbL + ((r * 128 + c * 2) ^ ((r & 7) << 4))) = (bf16_t)w;
        float pv = vic * sc;
        pv += __shfl_xor(pv, 1); pv += __shfl_xor(pv, 2);
        pv += __shfl_xor(pv, 4); pv += __shfl_xor(pv, 8);
        if (lr == 0) vpL[r * 4 + wq] = pv;
      }
  }
  __syncthreads();

  // vp finalize (eh==0 only)
  if (eh == 0 && tid < 64) {
    float s = vpL[tid * 4 + 0] + vpL[tid * 4 + 1] + vpL[tid * 4 + 2] + vpL[tid * 4 + 3];
    out[VP_OFF + tb + tid] = s;
  }

  // sbias = w @ (bt+char)_cols -> phase-B accumulators  (wave: 32 rows x 16 e)
  f32x4 acc[2] = {{0,0,0,0},{0,0,0,0}};
  {
    int eg = eh * 64 + wq * 16 + lr;
    #pragma unroll
    for (int ks = 0; ks < 2; ++ks) {
      int k0 = ks * 32 + lk;
      bf16x8 b = *(const bf16x8*)(bct + eg * 64 + k0);
      #pragma unroll
      for (int rg = 0; rg < 2; ++rg) {
        int r = wr + rg * 16 + lr;
        bf16x8 a = *(const bf16x8*)((char*)wbL + ((r * 128 + k0 * 2) ^ ((r & 7) << 4)));
        acc[rg] = mfma16(a, b, acc[rg]);
      }
    }
  }

  // ---------------- phase B: acc += sum_m w[:,m] * (x @ Wt[m])[:, e-cols]  (barrier-free)
  const char* bbase = wttc + (size_t)(((eh * 64 + wq * 16 + lr) * 32 + lg * 8) * 2);
  bf16x8 F0[4], F1[4], F2[4], F3[4];
  loadF(F0, bbase, 0);
  loadF(F1, bbase, 1);
  loadF(F2, bbase, 2);

  for (int it = 0; it < 16; ++it) {
    const int base = it * 4;
    f32x4 wc[8];
    #pragma unroll
    for (int rg = 0; rg < 2; ++rg)
      #pragma unroll
      for (int jj = 0; jj < 4; ++jj)
        wc[rg * 4 + jj] = *(const f32x4*)(&wL[(wr + rg * 16 + lj4 + jj) * 68 + base]);
    int n4 = base + 4 > 63 ? 63 : base + 4;
    int n5 = base + 5 > 63 ? 63 : base + 5;
    int n6 = base + 6 > 63 ? 63 : base + 6;
    loadF(F3, bbase, base + 3);
    computeT<0>(F0, wc, aX, acc);
    loadF(F0, bbase, n4);
    computeT<1>(F1, wc, aX, acc);
    loadF(F1, bbase, n5);
    computeT<2>(F2, wc, aX, acc);
    loadF(F2, bbase, n6);
    computeT<3>(F3, wc, aX, acc);
  }

  // ---------------- phase C: selected(this half) -> LDS, integrate partial, atomicAdd
  #pragma unroll
  for (int rg = 0; rg < 2; ++rg)
    #pragma unroll
    for (int j = 0; j < 4; ++j) {
      int r = wr + rg * 16 + lj4 + j;
      int cl = wq * 16 + lr;
      *(bf16_t*)((char*)selL + ((r * 128 + cl * 2) ^ ((r & 7) << 4))) = (bf16_t)acc[rg][j];
    }
  __syncthreads();

  #pragma unroll
  for (int cg = 0; cg < 2; ++cg) {
    int c = wq * 32 + cg * 16 + lr;
    f32x4 a[2] = {{0,0,0,0},{0,0,0,0}};
    #pragma unroll
    for (int ks = 0; ks < 2; ++ks) {
      int k0 = ks * 32 + lk;
      bf16x8 b = *(const bf16x8*)(Wit + c * 256 + 128 + eh * 64 + k0);
      #pragma unroll
      for (int rg = 0; rg < 2; ++rg) {
        int r = wr + rg * 16 + lr;
        bf16x8 av = *(const bf16x8*)((char*)selL + ((r * 128 + k0 * 2) ^ ((r & 7) << 4)));
        a[rg] = mfma16(av, b, a[rg]);
      }
    }
    if (eh == 0) {
      #pragma unroll
      for (int ks = 0; ks < 4; ++ks) {
        bf16x8 b = *(const bf16x8*)(Wit + c * 256 + ks * 32 + lk);
        #pragma unroll
        for (int rg = 0; rg < 2; ++rg) a[rg] = mfma16(aX[rg][ks], b, a[rg]);
      }
    }
    float bb = (eh == 0) ? bi[c] : 0.0f;
    #pragma unroll
    for (int rg = 0; rg < 2; ++rg)
      #pragma unroll
      for (int j = 0; j < 4; ++j)
        atomicAdd(&out[(tb + wr + rg * 16 + lj4 + j) * 128 + c], a[rg][j] + bb);
  }
}

// ---------------------------------------------------------------- launch
extern "C" void kernel_launch(void* const* d_in, const int* in_sizes, int n_in,
                              void* d_out, int out_size, void* d_ws, size_t ws_size,
                              hipStream_t stream)
{
  (void)in_sizes; (void)n_in; (void)ws_size;
  const float* x   = (const float*)d_in[0];
  const float* ctx = (const float*)d_in[1];
  const float* Wt  = (const float*)d_in[2];
  const float* bt  = (const float*)d_in[3];
  const float* ch  = (const float*)d_in[4];
  const float* Wg  = (const float*)d_in[5];
  const float* bg  = (const float*)d_in[6];
  const float* Wv  = (const float*)d_in[7];
  const float* bv  = (const float*)d_in[8];
  const float* O   = (const float*)d_in[9];
  const float* W1  = (const float*)d_in[10];
  const float* b1  = (const float*)d_in[11];
  const float* W2  = (const float*)d_in[12];
  const float* b2  = (const float*)d_in[13];
  const float* Wi  = (const float*)d_in[14];
  const float* bi  = (const float*)d_in[15];
  float* out = (float*)d_out;
  char* ws = (char*)d_ws;

  hipMemsetAsync(d_out, 0, (size_t)out_size * 4, stream);
  kprep<<<186, 256, 0, stream>>>(Wt, bt, ch, Wg, Wv, bv, O, W1, W2, Wi, ws);
  kfused<<<256, 512, 0, stream>>>(x, ctx, b1, b2, bg, bi, ws, out);
}

// Round 6
// 156.323 us; speedup vs baseline: 1.0221x; 1.0221x over previous
//
#include <hip/hip_runtime.h>
#include <hip/hip_bf16.h>

// MechanismGrabber: B=2,S=4096,D=128,M=64. Outputs: integrated [8192,128] f32, vp [8192] f32.
// R6: fused kernel, 512 blocks (256 tokTiles of 32 rows x 2 e-halves), 256 thr = 4 waves,
// each wave = all 32 rows x distinct 16 e-cols (no duplicate B loads). LDS 46 KB ->
// 2 blocks/CU (2 waves/SIMD from independent blocks). Phase B: depth-6, 8 rotating buffers.

typedef __bf16 bf16_t;
typedef __bf16 bf16x8 __attribute__((ext_vector_type(8)));
typedef float  f32x4  __attribute__((ext_vector_type(4)));

// ws layout (bytes)
#define WS_WTT      0u          // bf16 [m][ks(4)][e(128)][g(4)][j(8)]  (frag-major Wt^T), 2 MB
#define WS_W1T      2097152u    // bf16 [256 out][256 in]
#define WS_W2T      2228224u    // bf16 [64 out][256 in]
#define WS_OT       2260992u    // bf16 [64 out][64 in]
#define WS_WG       2269184u    // bf16 [64][128]
#define WS_U        2285568u    // bf16 [64][128]
#define WS_CVEC     2301952u    // f32  [64]
#define WS_BCT      2302208u    // bf16 [128 e][64 m]  (bt+char)^T
#define WS_WIT      2318592u    // bf16 [128 out][256 in]

#define VP_OFF 1048576

__device__ __forceinline__ f32x4 mfma16(bf16x8 a, bf16x8 b, f32x4 c) {
  return __builtin_amdgcn_mfma_f32_16x16x32_bf16(a, b, c, 0, 0, 0);
}

__device__ __forceinline__ float gelu_exact(float v) {
  return 0.5f * v * (1.0f + erff(v * 0.70710678118654752f));
}
__device__ __forceinline__ float sigmoidf_(float v) {
  return 1.0f / (1.0f + __expf(-v));
}

__device__ __forceinline__ bf16x8 cvt8(float4 v0, float4 v1) {
  bf16x8 a;
  a[0] = (bf16_t)v0.x; a[1] = (bf16_t)v0.y; a[2] = (bf16_t)v0.z; a[3] = (bf16_t)v0.w;
  a[4] = (bf16_t)v1.x; a[5] = (bf16_t)v1.y; a[6] = (bf16_t)v1.z; a[7] = (bf16_t)v1.w;
  return a;
}

// ---------------------------------------------------------------- kernel P (same as R5)
__global__ __launch_bounds__(256) void kprep(
    const float* __restrict__ Wt, const float* __restrict__ bt,
    const float* __restrict__ ch, const float* __restrict__ Wg,
    const float* __restrict__ Wv, const float* __restrict__ bv,
    const float* __restrict__ O, const float* __restrict__ W1,
    const float* __restrict__ W2, const float* __restrict__ Wi,
    char* __restrict__ ws)
{
  const int bid = blockIdx.x, tid = threadIdx.x;
  if (bid < 128) {
    const int m = bid >> 1, half = bid & 1;
    const float* wtm = Wt + m * 16384;
    bf16_t* wtt = (bf16_t*)(ws + WS_WTT) + m * 16384;
    const int ks = half * 2 + (tid >> 7), e = tid & 127;
    bf16_t tmp[32];
    #pragma unroll
    for (int dd = 0; dd < 32; ++dd)
      tmp[dd] = (bf16_t)wtm[(ks * 32 + dd) * 128 + e];
    bf16_t* dst = wtt + ks * 4096 + e * 32;
    #pragma unroll
    for (int g = 0; g < 4; ++g)
      *(bf16x8*)(dst + g * 8) = *(const bf16x8*)(tmp + g * 8);
  } else if (bid < 144) {
    int base = (bid - 128) * 256 + tid;
    int k = base >> 4, c0 = (base & 15) * 16;
    bf16_t* o = (bf16_t*)(ws + WS_W1T);
    #pragma unroll
    for (int j = 0; j < 16; ++j) o[(c0 + j) * 256 + k] = (bf16_t)W1[k * 256 + c0 + j];
  } else if (bid < 146) {
    int base = (bid - 144) * 256 + tid;
    int k = base >> 1, c0 = (base & 1) * 32;
    bf16_t* o = (bf16_t*)(ws + WS_W2T);
    #pragma unroll
    for (int j = 0; j < 32; ++j) o[(c0 + j) * 256 + k] = (bf16_t)W2[k * 64 + c0 + j];
  } else if (bid == 146) {
    int k = tid >> 2, c0 = (tid & 3) * 16;
    bf16_t* o = (bf16_t*)(ws + WS_OT);
    #pragma unroll
    for (int j = 0; j < 16; ++j) o[(c0 + j) * 64 + k] = (bf16_t)O[k * 64 + c0 + j];
  } else if (bid == 147) {
    bf16_t* o = (bf16_t*)(ws + WS_WG);
    #pragma unroll
    for (int j = 0; j < 32; ++j) o[tid * 32 + j] = (bf16_t)Wg[tid * 32 + j];
  } else if (bid == 148) {
    bf16_t* o = (bf16_t*)(ws + WS_BCT);
    #pragma unroll
    for (int i = 0; i < 4; ++i) {
      int task = tid + i * 256;
      int m = task >> 4, e0 = (task & 15) * 8;
      #pragma unroll
      for (int j = 0; j < 8; ++j)
        o[(e0 + j) * 64 + m] = (bf16_t)(bt[m * 128 + e0 + j] + ch[m * 128 + e0 + j]);
    }
  } else if (bid < 153) {
    int base = (bid - 149) * 256 + tid;
    int k = base >> 2, c0 = (base & 3) * 32;
    bf16_t* o = (bf16_t*)(ws + WS_WIT);
    #pragma unroll
    for (int j = 0; j < 32; ++j) o[(c0 + j) * 256 + k] = (bf16_t)Wi[k * 128 + c0 + j];
  } else if (bid < 185) {
    int task = (bid - 153) * 256 + tid;   // 8192 tasks: u[m][d]
    int m = task >> 7, d = task & 127;
    const float4* wp = (const float4*)(Wt + m * 16384 + d * 128);
    const float4* vp = (const float4*)(Wv + m * 128);
    float s = 0.f;
    #pragma unroll
    for (int i = 0; i < 32; ++i) {
      float4 a = wp[i], b = vp[i];
      s += a.x * b.x + a.y * b.y + a.z * b.z + a.w * b.w;
    }
    ((bf16_t*)(ws + WS_U))[m * 128 + d] = (bf16_t)s;
  } else {
    if (tid < 64) {
      int m = tid;
      const float4* bp = (const float4*)(bt + m * 128);
      const float4* cp = (const float4*)(ch + m * 128);
      const float4* vp = (const float4*)(Wv + m * 128);
      float s = bv[m];
      #pragma unroll
      for (int i = 0; i < 32; ++i) {
        float4 a = bp[i], c = cp[i], b = vp[i];
        s += (a.x + c.x) * b.x + (a.y + c.y) * b.y + (a.z + c.z) * b.z + (a.w + c.w) * b.w;
      }
      ((float*)(ws + WS_CVEC))[m] = s;
    }
  }
}

// ---------------------------------------------------------------- fused kernel
__device__ __forceinline__ void loadF(bf16x8 (&F)[4], const char* bbase, int m) {
  const char* p = bbase + m * 32768;
  F[0] = *(const bf16x8*)(p);
  F[1] = *(const bf16x8*)(p + 8192);
  F[2] = *(const bf16x8*)(p + 16384);
  F[3] = *(const bf16x8*)(p + 24576);
}

// LDS layout (bytes): hL 0..16384 | scoresL 16384..24576 | wLT 24576..33792
// scbL 33792..37888 | wbL 37888..41984 | selL 41984..46080 | vpL 46080..46592
#define SM_BYTES 46592

__global__ __launch_bounds__(256, 2) void kfused(
    const float* __restrict__ x, const float* __restrict__ ctx,
    const float* __restrict__ b1, const float* __restrict__ b2,
    const float* __restrict__ bg, const float* __restrict__ bi,
    char* __restrict__ ws, float* __restrict__ out)
{
  __shared__ char sm[SM_BYTES];
  bf16_t* hL      = (bf16_t*)sm;               // [32][256] bf16 swz, 16 KB
  float*  scoresL = (float*)(sm + 16384);      // [32][64]  f32, 8 KB
  float*  wLT     = (float*)(sm + 24576);      // [64 m][36] f32 (transposed w), 9 KB
  bf16_t* scbL    = (bf16_t*)(sm + 33792);     // [32][64]  bf16 swz, 4 KB
  bf16_t* wbL     = (bf16_t*)(sm + 37888);     // [32][64]  bf16 swz, 4 KB
  bf16_t* selL    = (bf16_t*)(sm + 41984);     // [32][64]  bf16 swz, 4 KB
  float*  vpL     = (float*)(sm + 46080);      // [32][4]

  const int tid = threadIdx.x;
  const int lane = tid & 63, wq = tid >> 6;    // 4 waves, wq = e/mech quarter
  const int tb = (blockIdx.x >> 1) * 32;
  const int eh = blockIdx.x & 1;
  const int lr = lane & 15;
  const int lg = lane >> 4;
  const int lk = lg * 8;
  const int lj4 = lg * 4;

  const bf16_t* W1t = (const bf16_t*)(ws + WS_W1T);
  const bf16_t* W2t = (const bf16_t*)(ws + WS_W2T);
  const bf16_t* Ot  = (const bf16_t*)(ws + WS_OT);
  const bf16_t* Wgb = (const bf16_t*)(ws + WS_WG);
  const bf16_t* Ub  = (const bf16_t*)(ws + WS_U);
  const float*  cv  = (const float*)(ws + WS_CVEC);
  const bf16_t* bct = (const bf16_t*)(ws + WS_BCT);
  const bf16_t* Wit = (const bf16_t*)(ws + WS_WIT);
  const char*  wttc = (const char*)(ws + WS_WTT);

  // persistent x A-frags for this block's 32 rows
  bf16x8 aX[2][4];
  #pragma unroll
  for (int rg = 0; rg < 2; ++rg) {
    const float* xr = x + (tb + rg * 16 + lr) * 128;
    #pragma unroll
    for (int ks = 0; ks < 4; ++ks)
      aX[rg][ks] = cvt8(*(const float4*)(xr + ks * 32 + lk),
                        *(const float4*)(xr + ks * 32 + lk + 4));
  }

  // ---------------- GEMM1: [32,256]@W1 -> gelu -> hL  (wave: 32 rows x 64 cols, ks-outer)
  {
    f32x4 a1[4][2] = {{{0,0,0,0},{0,0,0,0}},{{0,0,0,0},{0,0,0,0}},
                      {{0,0,0,0},{0,0,0,0}},{{0,0,0,0},{0,0,0,0}}};
    #pragma unroll
    for (int ks = 0; ks < 8; ++ks) {
      bf16x8 af[2];
      if (ks < 4) {
        af[0] = aX[0][ks]; af[1] = aX[1][ks];
      } else {
        #pragma unroll
        for (int rg = 0; rg < 2; ++rg) {
          const float* cr = ctx + (tb + rg * 16 + lr) * 128 + (ks - 4) * 32 + lk;
          af[rg] = cvt8(*(const float4*)cr, *(const float4*)(cr + 4));
        }
      }
      #pragma unroll
      for (int cg = 0; cg < 4; ++cg) {
        bf16x8 b = *(const bf16x8*)(W1t + (wq * 64 + cg * 16 + lr) * 256 + ks * 32 + lk);
        a1[cg][0] = mfma16(af[0], b, a1[cg][0]);
        a1[cg][1] = mfma16(af[1], b, a1[cg][1]);
      }
    }
    #pragma unroll
    for (int cg = 0; cg < 4; ++cg) {
      int c = wq * 64 + cg * 16 + lr;
      float bb = b1[c];
      #pragma unroll
      for (int rg = 0; rg < 2; ++rg)
        #pragma unroll
        for (int j = 0; j < 4; ++j) {
          int r = rg * 16 + lj4 + j;
          float v = gelu_exact(a1[cg][rg][j] + bb);
          *(bf16_t*)((char*)hL + ((r * 512 + c * 2) ^ ((r & 7) << 4))) = (bf16_t)v;
        }
    }
  }
  __syncthreads();

  // ---------------- GEMM2: h@W2 + b2 -> logits  (wave: 32 rows x 16 mechs)
  {
    int c = wq * 16 + lr;
    f32x4 l[2] = {{0,0,0,0},{0,0,0,0}};
    #pragma unroll
    for (int ks = 0; ks < 8; ++ks) {
      int k0 = ks * 32 + lk;
      bf16x8 b = *(const bf16x8*)(W2t + c * 256 + k0);
      #pragma unroll
      for (int rg = 0; rg < 2; ++rg) {
        int r = rg * 16 + lr;
        bf16x8 a = *(const bf16x8*)((char*)hL + ((r * 512 + k0 * 2) ^ ((r & 7) << 4)));
        l[rg] = mfma16(a, b, l[rg]);
      }
    }
    float bb = b2[c];
    #pragma unroll
    for (int rg = 0; rg < 2; ++rg)
      #pragma unroll
      for (int j = 0; j < 4; ++j)
        scoresL[(rg * 16 + lj4 + j) * 64 + c] = l[rg][j] + bb;
  }
  __syncthreads();

  // ---------------- softmax over 64 mechs (8 threads/row x 8 vals; 32 rows)
  {
    int row = tid >> 3, i = tid & 7;
    float v[8];
    #pragma unroll
    for (int j = 0; j < 8; ++j) v[j] = scoresL[row * 64 + i * 8 + j];
    float mx = v[0];
    #pragma unroll
    for (int j = 1; j < 8; ++j) mx = fmaxf(mx, v[j]);
    mx = fmaxf(mx, __shfl_xor(mx, 1));
    mx = fmaxf(mx, __shfl_xor(mx, 2));
    mx = fmaxf(mx, __shfl_xor(mx, 4));
    float sum = 0.f;
    #pragma unroll
    for (int j = 0; j < 8; ++j) { v[j] = __expf(v[j] - mx); sum += v[j]; }
    sum += __shfl_xor(sum, 1);
    sum += __shfl_xor(sum, 2);
    sum += __shfl_xor(sum, 4);
    float inv = 1.0f / sum;
    #pragma unroll
    for (int j = 0; j < 8; ++j) {
      float s = v[j] * inv;
      int cc = i * 8 + j;
      scoresL[row * 64 + cc] = s;
      *(bf16_t*)((char*)scbL + ((row * 128 + cc * 2) ^ ((row & 7) << 4))) = (bf16_t)s;
    }
  }
  __syncthreads();

  // ---------------- gates / timing / victory / w  (wave: 32 rows x 16 mechs)
  {
    const int c = wq * 16 + lr;
    f32x4 g[2] = {{0,0,0,0},{0,0,0,0}};
    #pragma unroll
    for (int ks = 0; ks < 2; ++ks) {
      int k0 = ks * 32 + lk;
      bf16x8 b = *(const bf16x8*)(Ot + c * 64 + k0);
      #pragma unroll
      for (int rg = 0; rg < 2; ++rg) {
        int r = rg * 16 + lr;
        bf16x8 a = *(const bf16x8*)((char*)scbL + ((r * 128 + k0 * 2) ^ ((r & 7) << 4)));
        g[rg] = mfma16(a, b, g[rg]);
      }
    }
    f32x4 t[2] = {{0,0,0,0},{0,0,0,0}};
    f32x4 v[2] = {{0,0,0,0},{0,0,0,0}};
    #pragma unroll
    for (int ks = 0; ks < 4; ++ks) {
      bf16x8 bT = *(const bf16x8*)(Wgb + c * 128 + ks * 32 + lk);
      bf16x8 bV = *(const bf16x8*)(Ub  + c * 128 + ks * 32 + lk);
      #pragma unroll
      for (int rg = 0; rg < 2; ++rg) {
        t[rg] = mfma16(aX[rg][ks], bT, t[rg]);
        v[rg] = mfma16(aX[rg][ks], bV, v[rg]);
      }
    }
    float bgc = bg[c], cvc = cv[c];
    #pragma unroll
    for (int rg = 0; rg < 2; ++rg)
      #pragma unroll
      for (int j = 0; j < 4; ++j) {
        int r = rg * 16 + lj4 + j;
        float gate = 1.0f + tanhf(g[rg][j]);
        float tim  = sigmoidf_(t[rg][j] + bgc);
        float vic  = sigmoidf_(v[rg][j] + cvc);
        float sc   = scoresL[r * 64 + c];
        float w    = gate * sc * tim;
        wLT[c * 36 + r] = w;          // transposed: [m][row], stride 36 (16B-aligned rows)
        *(bf16_t*)((char*)wbL + ((r * 128 + c * 2) ^ ((r & 7) << 4))) = (bf16_t)w;
        float pv = vic * sc;
        pv += __shfl_xor(pv, 1); pv += __shfl_xor(pv, 2);
        pv += __shfl_xor(pv, 4); pv += __shfl_xor(pv, 8);
        if (lr == 0) vpL[r * 4 + wq] = pv;
      }
  }
  __syncthreads();

  // vp finalize (eh==0 only)
  if (eh == 0 && tid < 32) {
    float s = vpL[tid * 4 + 0] + vpL[tid * 4 + 1] + vpL[tid * 4 + 2] + vpL[tid * 4 + 3];
    out[VP_OFF + tb + tid] = s;
  }

  // sbias = w @ (bt+char)_cols -> phase-B accumulators  (wave: 32 rows x 16 e)
  f32x4 acc[2] = {{0,0,0,0},{0,0,0,0}};
  {
    int eg = eh * 64 + wq * 16 + lr;
    #pragma unroll
    for (int ks = 0; ks < 2; ++ks) {
      int k0 = ks * 32 + lk;
      bf16x8 b = *(const bf16x8*)(bct + eg * 64 + k0);
      #pragma unroll
      for (int rg = 0; rg < 2; ++rg) {
        int r = rg * 16 + lr;
        bf16x8 a = *(const bf16x8*)((char*)wbL + ((r * 128 + k0 * 2) ^ ((r & 7) << 4)));
        acc[rg] = mfma16(a, b, acc[rg]);
      }
    }
  }

  // ---------------- phase B: acc += sum_m w[:,m] * (x @ Wt[m])[:, e-cols]
  // depth-6 pipeline, 8 rotating buffers, fully unrolled (static reg indices).
  const char* bbase = wttc + (size_t)(((eh * 64 + wq * 16 + lr) * 32 + lg * 8) * 2);
  bf16x8 F[8][4];
  loadF(F[0], bbase, 0);
  loadF(F[1], bbase, 1);
  loadF(F[2], bbase, 2);
  loadF(F[3], bbase, 3);
  loadF(F[4], bbase, 4);
  loadF(F[5], bbase, 5);

  #pragma unroll
  for (int it = 0; it < 8; ++it) {
    const int base = it * 8;
    #pragma unroll
    for (int s = 0; s < 8; ++s) {
      const int m = base + s;
      int mp = m + 6; if (mp > 63) mp = 63;
      loadF(F[(s + 6) & 7], bbase, mp);
      f32x4 w0 = *(const f32x4*)(&wLT[m * 36 + lj4]);
      f32x4 w1 = *(const f32x4*)(&wLT[m * 36 + 16 + lj4]);
      f32x4 y0 = {0.f,0.f,0.f,0.f}, y1 = {0.f,0.f,0.f,0.f};
      #pragma unroll
      for (int ks = 0; ks < 4; ++ks) {
        y0 = mfma16(aX[0][ks], F[s][ks], y0);
        y1 = mfma16(aX[1][ks], F[s][ks], y1);
      }
      #pragma unroll
      for (int jj = 0; jj < 4; ++jj) {
        acc[0][jj] += w0[jj] * y0[jj];
        acc[1][jj] += w1[jj] * y1[jj];
      }
    }
  }

  // ---------------- phase C: selected(this half) -> LDS, integrate partial, atomicAdd
  #pragma unroll
  for (int rg = 0; rg < 2; ++rg)
    #pragma unroll
    for (int j = 0; j < 4; ++j) {
      int r = rg * 16 + lj4 + j;
      int cl = wq * 16 + lr;
      *(bf16_t*)((char*)selL + ((r * 128 + cl * 2) ^ ((r & 7) << 4))) = (bf16_t)acc[rg][j];
    }
  __syncthreads();

  #pragma unroll
  for (int cg = 0; cg < 2; ++cg) {
    int c = wq * 32 + cg * 16 + lr;
    f32x4 a[2] = {{0,0,0,0},{0,0,0,0}};
    #pragma unroll
    for (int ks = 0; ks < 2; ++ks) {
      int k0 = ks * 32 + lk;
      bf16x8 b = *(const bf16x8*)(Wit + c * 256 + 128 + eh * 64 + k0);
      #pragma unroll
      for (int rg = 0; rg < 2; ++rg) {
        int r = rg * 16 + lr;
        bf16x8 av = *(const bf16x8*)((char*)selL + ((r * 128 + k0 * 2) ^ ((r & 7) << 4)));
        a[rg] = mfma16(av, b, a[rg]);
      }
    }
    if (eh == 0) {
      #pragma unroll
      for (int ks = 0; ks < 4; ++ks) {
        bf16x8 b = *(const bf16x8*)(Wit + c * 256 + ks * 32 + lk);
        #pragma unroll
        for (int rg = 0; rg < 2; ++rg) a[rg] = mfma16(aX[rg][ks], b, a[rg]);
      }
    }
    float bb = (eh == 0) ? bi[c] : 0.0f;
    #pragma unroll
    for (int rg = 0; rg < 2; ++rg)
      #pragma unroll
      for (int j = 0; j < 4; ++j)
        atomicAdd(&out[(tb + rg * 16 + lj4 + j) * 128 + c], a[rg][j] + bb);
  }
}

// ---------------------------------------------------------------- launch
extern "C" void kernel_launch(void* const* d_in, const int* in_sizes, int n_in,
                              void* d_out, int out_size, void* d_ws, size_t ws_size,
                              hipStream_t stream)
{
  (void)in_sizes; (void)n_in; (void)ws_size;
  const float* x   = (const float*)d_in[0];
  const float* ctx = (const float*)d_in[1];
  const float* Wt  = (const float*)d_in[2];
  const float* bt  = (const float*)d_in[3];
  const float* ch  = (const float*)d_in[4];
  const float* Wg  = (const float*)d_in[5];
  const float* bg  = (const float*)d_in[6];
  const float* Wv  = (const float*)d_in[7];
  const float* bv  = (const float*)d_in[8];
  const float* O   = (const float*)d_in[9];
  const float* W1  = (const float*)d_in[10];
  const float* b1  = (const float*)d_in[11];
  const float* W2  = (const float*)d_in[12];
  const float* b2  = (const float*)d_in[13];
  const float* Wi  = (const float*)d_in[14];
  const float* bi  = (const float*)d_in[15];
  float* out = (float*)d_out;
  char* ws = (char*)d_ws;

  hipMemsetAsync(d_out, 0, (size_t)out_size * 4, stream);
  kprep<<<186, 256, 0, stream>>>(Wt, bt, ch, Wg, Wv, bv, O, W1, W2, Wi, ws);
  kfused<<<512, 256, 0, stream>>>(x, ctx, b1, b2, bg, bi, ws, out);
}

// Round 7
// 152.671 us; speedup vs baseline: 1.0465x; 1.0239x over previous
//
#include <hip/hip_runtime.h>
#include <hip/hip_bf16.h>

// MechanismGrabber: B=2,S=4096,D=128,M=64. Outputs: integrated [8192,128] f32, vp [8192] f32.
// R7: split pipeline, no atomics, selector deduplicated, fast transcendentals.
//   kprep  : weight transposes, u_m = Wt[m]@Wv[m], cvec, bct.
//   kselect: per 32-token tile: MLP+softmax+gates/timing/victory -> wT (f32 [64][8192]),
//            sbias (f32 [8192][128]), vp.
//   kmech  : 512 blocks = 128 tokTiles x 2 ehalf x 2 mhalf; sel{mh} += sum_m w*(x@Wt[m]).
//            16 MFMA : 4 L2-loads per m per wave, depth-3 reg pipeline, no barriers in loop.
//   kinteg : out = [x | sel0+sel1+sbias] @ Wi + bi.

typedef __bf16 bf16_t;
typedef __bf16 bf16x8 __attribute__((ext_vector_type(8)));
typedef float  f32x4  __attribute__((ext_vector_type(4)));

// ws layout (bytes)
#define WS_WTT      0u          // bf16 [m][ks(4)][e(128)][g(4)][j(8)] frag-major Wt^T, 2 MB
#define WS_W1T      2097152u    // bf16 [256][256]
#define WS_W2T      2228224u    // bf16 [64][256]
#define WS_OT       2260992u    // bf16 [64][64]
#define WS_WG       2269184u    // bf16 [64][128]
#define WS_U        2285568u    // bf16 [64][128]
#define WS_CVEC     2301952u    // f32  [64]
#define WS_BCT      2302208u    // bf16 [128 e][64 m]
#define WS_WIT      2318592u    // bf16 [128][256]
#define WS_WT       2384128u    // f32  [64 m][8192 tok]  (w transposed), 2 MB
#define WS_SBIAS    4481280u    // f32  [8192][128], 4 MB
#define WS_SEL0     8675584u    // f32  [8192][128], 4 MB
#define WS_SEL1     12869888u   // f32  [8192][128], 4 MB

#define VP_OFF 1048576

__device__ __forceinline__ f32x4 mfma16(bf16x8 a, bf16x8 b, f32x4 c) {
  return __builtin_amdgcn_mfma_f32_16x16x32_bf16(a, b, c, 0, 0, 0);
}

// branchless erf, Abramowitz-Stegun 7.1.26 (|err| <= 1.5e-7), __expf-based
__device__ __forceinline__ float erf_fast(float x) {
  float ax = fabsf(x);
  float t = 1.0f / (1.0f + 0.3275911f * ax);
  float p = t * (0.254829592f + t * (-0.284496736f + t * (1.421413741f +
            t * (-1.453152027f + t * 1.061405429f))));
  float y = 1.0f - p * __expf(-ax * ax);
  return copysignf(y, x);
}
__device__ __forceinline__ float gelu_fast(float v) {
  return 0.5f * v * (1.0f + erf_fast(v * 0.70710678118654752f));
}
__device__ __forceinline__ float tanh_fast(float x) {
  float xc = fminf(fmaxf(x, -15.f), 15.f);
  float e = __expf(2.0f * xc);
  return (e - 1.0f) / (e + 1.0f);
}
__device__ __forceinline__ float sigmoidf_(float v) {
  return 1.0f / (1.0f + __expf(-v));
}

__device__ __forceinline__ bf16x8 cvt8(float4 v0, float4 v1) {
  bf16x8 a;
  a[0] = (bf16_t)v0.x; a[1] = (bf16_t)v0.y; a[2] = (bf16_t)v0.z; a[3] = (bf16_t)v0.w;
  a[4] = (bf16_t)v1.x; a[5] = (bf16_t)v1.y; a[6] = (bf16_t)v1.z; a[7] = (bf16_t)v1.w;
  return a;
}

// ---------------------------------------------------------------- kernel P
__global__ __launch_bounds__(256) void kprep(
    const float* __restrict__ Wt, const float* __restrict__ bt,
    const float* __restrict__ ch, const float* __restrict__ Wg,
    const float* __restrict__ Wv, const float* __restrict__ bv,
    const float* __restrict__ O, const float* __restrict__ W1,
    const float* __restrict__ W2, const float* __restrict__ Wi,
    char* __restrict__ ws)
{
  const int bid = blockIdx.x, tid = threadIdx.x;
  if (bid < 128) {
    const int m = bid >> 1, half = bid & 1;
    const float* wtm = Wt + m * 16384;
    bf16_t* wtt = (bf16_t*)(ws + WS_WTT) + m * 16384;
    const int ks = half * 2 + (tid >> 7), e = tid & 127;
    bf16_t tmp[32];
    #pragma unroll
    for (int dd = 0; dd < 32; ++dd)
      tmp[dd] = (bf16_t)wtm[(ks * 32 + dd) * 128 + e];
    bf16_t* dst = wtt + ks * 4096 + e * 32;
    #pragma unroll
    for (int g = 0; g < 4; ++g)
      *(bf16x8*)(dst + g * 8) = *(const bf16x8*)(tmp + g * 8);
  } else if (bid < 144) {
    int base = (bid - 128) * 256 + tid;
    int k = base >> 4, c0 = (base & 15) * 16;
    bf16_t* o = (bf16_t*)(ws + WS_W1T);
    #pragma unroll
    for (int j = 0; j < 16; ++j) o[(c0 + j) * 256 + k] = (bf16_t)W1[k * 256 + c0 + j];
  } else if (bid < 146) {
    int base = (bid - 144) * 256 + tid;
    int k = base >> 1, c0 = (base & 1) * 32;
    bf16_t* o = (bf16_t*)(ws + WS_W2T);
    #pragma unroll
    for (int j = 0; j < 32; ++j) o[(c0 + j) * 256 + k] = (bf16_t)W2[k * 64 + c0 + j];
  } else if (bid == 146) {
    int k = tid >> 2, c0 = (tid & 3) * 16;
    bf16_t* o = (bf16_t*)(ws + WS_OT);
    #pragma unroll
    for (int j = 0; j < 16; ++j) o[(c0 + j) * 64 + k] = (bf16_t)O[k * 64 + c0 + j];
  } else if (bid == 147) {
    bf16_t* o = (bf16_t*)(ws + WS_WG);
    #pragma unroll
    for (int j = 0; j < 32; ++j) o[tid * 32 + j] = (bf16_t)Wg[tid * 32 + j];
  } else if (bid == 148) {
    bf16_t* o = (bf16_t*)(ws + WS_BCT);
    #pragma unroll
    for (int i = 0; i < 4; ++i) {
      int task = tid + i * 256;
      int m = task >> 4, e0 = (task & 15) * 8;
      #pragma unroll
      for (int j = 0; j < 8; ++j)
        o[(e0 + j) * 64 + m] = (bf16_t)(bt[m * 128 + e0 + j] + ch[m * 128 + e0 + j]);
    }
  } else if (bid < 153) {
    int base = (bid - 149) * 256 + tid;
    int k = base >> 2, c0 = (base & 3) * 32;
    bf16_t* o = (bf16_t*)(ws + WS_WIT);
    #pragma unroll
    for (int j = 0; j < 32; ++j) o[(c0 + j) * 256 + k] = (bf16_t)Wi[k * 128 + c0 + j];
  } else if (bid < 185) {
    int task = (bid - 153) * 256 + tid;   // u[m][d]
    int m = task >> 7, d = task & 127;
    const float4* wp = (const float4*)(Wt + m * 16384 + d * 128);
    const float4* vp = (const float4*)(Wv + m * 128);
    float s = 0.f;
    #pragma unroll
    for (int i = 0; i < 32; ++i) {
      float4 a = wp[i], b = vp[i];
      s += a.x * b.x + a.y * b.y + a.z * b.z + a.w * b.w;
    }
    ((bf16_t*)(ws + WS_U))[m * 128 + d] = (bf16_t)s;
  } else {
    if (tid < 64) {
      int m = tid;
      const float4* bp = (const float4*)(bt + m * 128);
      const float4* cp = (const float4*)(ch + m * 128);
      const float4* vp = (const float4*)(Wv + m * 128);
      float s = bv[m];
      #pragma unroll
      for (int i = 0; i < 32; ++i) {
        float4 a = bp[i], c = cp[i], b = vp[i];
        s += (a.x + c.x) * b.x + (a.y + c.y) * b.y + (a.z + c.z) * b.z + (a.w + c.w) * b.w;
      }
      ((float*)(ws + WS_CVEC))[m] = s;
    }
  }
}

// ---------------------------------------------------------------- kernel S (selector)
__global__ __launch_bounds__(256) void kselect(
    const float* __restrict__ x, const float* __restrict__ ctx,
    const float* __restrict__ b1, const float* __restrict__ b2,
    const float* __restrict__ bg,
    char* __restrict__ ws, float* __restrict__ out)
{
  __shared__ char sm[43008];
  bf16_t* hL      = (bf16_t*)sm;               // [32][256] swz, 16 KB
  float*  scoresL = (float*)(sm + 16384);      // [32][64], 8 KB
  float*  wLT     = (float*)(sm + 24576);      // [64 m][36] f32, 9.2 KB
  bf16_t* scbL    = (bf16_t*)(sm + 33792);     // [32][64] swz, 4 KB
  bf16_t* wbL     = (bf16_t*)(sm + 37888);     // [32][64] swz, 4 KB
  float*  vpL     = (float*)(sm + 41984);      // [32][4]

  const int tid = threadIdx.x;
  const int lane = tid & 63, wq = tid >> 6;
  const int tb = blockIdx.x * 32;
  const int lr = lane & 15, lg = lane >> 4;
  const int lk = lg * 8, lj4 = lg * 4;

  const bf16_t* W1t = (const bf16_t*)(ws + WS_W1T);
  const bf16_t* W2t = (const bf16_t*)(ws + WS_W2T);
  const bf16_t* Ot  = (const bf16_t*)(ws + WS_OT);
  const bf16_t* Wgb = (const bf16_t*)(ws + WS_WG);
  const bf16_t* Ub  = (const bf16_t*)(ws + WS_U);
  const float*  cv  = (const float*)(ws + WS_CVEC);
  const bf16_t* bct = (const bf16_t*)(ws + WS_BCT);
  float* wT    = (float*)(ws + WS_WT);
  float* sbOut = (float*)(ws + WS_SBIAS);

  bf16x8 aX[2][4];
  #pragma unroll
  for (int rg = 0; rg < 2; ++rg) {
    const float* xr = x + (tb + rg * 16 + lr) * 128;
    #pragma unroll
    for (int ks = 0; ks < 4; ++ks)
      aX[rg][ks] = cvt8(*(const float4*)(xr + ks * 32 + lk),
                        *(const float4*)(xr + ks * 32 + lk + 4));
  }

  // GEMM1 -> gelu -> hL
  {
    f32x4 a1[4][2] = {{{0,0,0,0},{0,0,0,0}},{{0,0,0,0},{0,0,0,0}},
                      {{0,0,0,0},{0,0,0,0}},{{0,0,0,0},{0,0,0,0}}};
    #pragma unroll
    for (int ks = 0; ks < 8; ++ks) {
      bf16x8 af[2];
      if (ks < 4) {
        af[0] = aX[0][ks]; af[1] = aX[1][ks];
      } else {
        #pragma unroll
        for (int rg = 0; rg < 2; ++rg) {
          const float* cr = ctx + (tb + rg * 16 + lr) * 128 + (ks - 4) * 32 + lk;
          af[rg] = cvt8(*(const float4*)cr, *(const float4*)(cr + 4));
        }
      }
      #pragma unroll
      for (int cg = 0; cg < 4; ++cg) {
        bf16x8 b = *(const bf16x8*)(W1t + (wq * 64 + cg * 16 + lr) * 256 + ks * 32 + lk);
        a1[cg][0] = mfma16(af[0], b, a1[cg][0]);
        a1[cg][1] = mfma16(af[1], b, a1[cg][1]);
      }
    }
    #pragma unroll
    for (int cg = 0; cg < 4; ++cg) {
      int c = wq * 64 + cg * 16 + lr;
      float bb = b1[c];
      #pragma unroll
      for (int rg = 0; rg < 2; ++rg)
        #pragma unroll
        for (int j = 0; j < 4; ++j) {
          int r = rg * 16 + lj4 + j;
          float v = gelu_fast(a1[cg][rg][j] + bb);
          *(bf16_t*)((char*)hL + ((r * 512 + c * 2) ^ ((r & 7) << 4))) = (bf16_t)v;
        }
    }
  }
  __syncthreads();

  // GEMM2 -> logits
  {
    int c = wq * 16 + lr;
    f32x4 l[2] = {{0,0,0,0},{0,0,0,0}};
    #pragma unroll
    for (int ks = 0; ks < 8; ++ks) {
      int k0 = ks * 32 + lk;
      bf16x8 b = *(const bf16x8*)(W2t + c * 256 + k0);
      #pragma unroll
      for (int rg = 0; rg < 2; ++rg) {
        int r = rg * 16 + lr;
        bf16x8 a = *(const bf16x8*)((char*)hL + ((r * 512 + k0 * 2) ^ ((r & 7) << 4)));
        l[rg] = mfma16(a, b, l[rg]);
      }
    }
    float bb = b2[c];
    #pragma unroll
    for (int rg = 0; rg < 2; ++rg)
      #pragma unroll
      for (int j = 0; j < 4; ++j)
        scoresL[(rg * 16 + lj4 + j) * 64 + c] = l[rg][j] + bb;
  }
  __syncthreads();

  // softmax
  {
    int row = tid >> 3, i = tid & 7;
    float v[8];
    #pragma unroll
    for (int j = 0; j < 8; ++j) v[j] = scoresL[row * 64 + i * 8 + j];
    float mx = v[0];
    #pragma unroll
    for (int j = 1; j < 8; ++j) mx = fmaxf(mx, v[j]);
    mx = fmaxf(mx, __shfl_xor(mx, 1));
    mx = fmaxf(mx, __shfl_xor(mx, 2));
    mx = fmaxf(mx, __shfl_xor(mx, 4));
    float sum = 0.f;
    #pragma unroll
    for (int j = 0; j < 8; ++j) { v[j] = __expf(v[j] - mx); sum += v[j]; }
    sum += __shfl_xor(sum, 1);
    sum += __shfl_xor(sum, 2);
    sum += __shfl_xor(sum, 4);
    float inv = 1.0f / sum;
    #pragma unroll
    for (int j = 0; j < 8; ++j) {
      float s = v[j] * inv;
      int cc = i * 8 + j;
      scoresL[row * 64 + cc] = s;
      *(bf16_t*)((char*)scbL + ((row * 128 + cc * 2) ^ ((row & 7) << 4))) = (bf16_t)s;
    }
  }
  __syncthreads();

  // gates / timing / victory / w
  {
    const int c = wq * 16 + lr;
    f32x4 g[2] = {{0,0,0,0},{0,0,0,0}};
    #pragma unroll
    for (int ks = 0; ks < 2; ++ks) {
      int k0 = ks * 32 + lk;
      bf16x8 b = *(const bf16x8*)(Ot + c * 64 + k0);
      #pragma unroll
      for (int rg = 0; rg < 2; ++rg) {
        int r = rg * 16 + lr;
        bf16x8 a = *(const bf16x8*)((char*)scbL + ((r * 128 + k0 * 2) ^ ((r & 7) << 4)));
        g[rg] = mfma16(a, b, g[rg]);
      }
    }
    f32x4 t[2] = {{0,0,0,0},{0,0,0,0}};
    f32x4 v[2] = {{0,0,0,0},{0,0,0,0}};
    #pragma unroll
    for (int ks = 0; ks < 4; ++ks) {
      bf16x8 bT = *(const bf16x8*)(Wgb + c * 128 + ks * 32 + lk);
      bf16x8 bV = *(const bf16x8*)(Ub  + c * 128 + ks * 32 + lk);
      #pragma unroll
      for (int rg = 0; rg < 2; ++rg) {
        t[rg] = mfma16(aX[rg][ks], bT, t[rg]);
        v[rg] = mfma16(aX[rg][ks], bV, v[rg]);
      }
    }
    float bgc = bg[c], cvc = cv[c];
    #pragma unroll
    for (int rg = 0; rg < 2; ++rg)
      #pragma unroll
      for (int j = 0; j < 4; ++j) {
        int r = rg * 16 + lj4 + j;
        float gate = 1.0f + tanh_fast(g[rg][j]);
        float tim  = sigmoidf_(t[rg][j] + bgc);
        float vic  = sigmoidf_(v[rg][j] + cvc);
        float sc   = scoresL[r * 64 + c];
        float w    = gate * sc * tim;
        wLT[c * 36 + r] = w;
        *(bf16_t*)((char*)wbL + ((r * 128 + c * 2) ^ ((r & 7) << 4))) = (bf16_t)w;
        float pv = vic * sc;
        pv += __shfl_xor(pv, 1); pv += __shfl_xor(pv, 2);
        pv += __shfl_xor(pv, 4); pv += __shfl_xor(pv, 8);
        if (lr == 0) vpL[r * 4 + wq] = pv;
      }
  }
  __syncthreads();

  // vp
  if (tid < 32) {
    float s = vpL[tid * 4 + 0] + vpL[tid * 4 + 1] + vpL[tid * 4 + 2] + vpL[tid * 4 + 3];
    out[VP_OFF + tb + tid] = s;
  }
  // w transposed -> ws (coalesced 32B chunks)
  {
    int m = tid >> 2, r0 = (tid & 3) * 8;
    float4 v0 = *(const float4*)&wLT[m * 36 + r0];
    float4 v1 = *(const float4*)&wLT[m * 36 + r0 + 4];
    *(float4*)&wT[m * 8192 + tb + r0] = v0;
    *(float4*)&wT[m * 8192 + tb + r0 + 4] = v1;
  }
  // sbias = w @ (bt+char) (full 128 e)
  #pragma unroll
  for (int cg = 0; cg < 2; ++cg) {
    int eg = wq * 32 + cg * 16 + lr;
    f32x4 s[2] = {{0,0,0,0},{0,0,0,0}};
    #pragma unroll
    for (int ks = 0; ks < 2; ++ks) {
      int k0 = ks * 32 + lk;
      bf16x8 b = *(const bf16x8*)(bct + eg * 64 + k0);
      #pragma unroll
      for (int rg = 0; rg < 2; ++rg) {
        int r = rg * 16 + lr;
        bf16x8 a = *(const bf16x8*)((char*)wbL + ((r * 128 + k0 * 2) ^ ((r & 7) << 4)));
        s[rg] = mfma16(a, b, s[rg]);
      }
    }
    #pragma unroll
    for (int rg = 0; rg < 2; ++rg)
      #pragma unroll
      for (int j = 0; j < 4; ++j)
        sbOut[(tb + rg * 16 + lj4 + j) * 128 + eg] = s[rg][j];
  }
}

// ---------------------------------------------------------------- kernel M (mechanisms)
__device__ __forceinline__ void loadF(bf16x8 (&F)[4], const char* bbase, int mm) {
  const char* p = bbase + mm * 32768;
  F[0] = *(const bf16x8*)(p);
  F[1] = *(const bf16x8*)(p + 8192);
  F[2] = *(const bf16x8*)(p + 16384);
  F[3] = *(const bf16x8*)(p + 24576);
}

__device__ __forceinline__ void stepM(const bf16x8 (&F)[4], const float* wrow,
                                      const bf16x8 (&aX)[4][4], f32x4 (&acc)[4], int lj4) {
  f32x4 y[4] = {{0,0,0,0},{0,0,0,0},{0,0,0,0},{0,0,0,0}};
  #pragma unroll
  for (int ks = 0; ks < 4; ++ks) {
    y[0] = mfma16(aX[0][ks], F[ks], y[0]);
    y[1] = mfma16(aX[1][ks], F[ks], y[1]);
    y[2] = mfma16(aX[2][ks], F[ks], y[2]);
    y[3] = mfma16(aX[3][ks], F[ks], y[3]);
  }
  #pragma unroll
  for (int rg = 0; rg < 4; ++rg) {
    f32x4 wv = *(const f32x4*)(wrow + rg * 16 + lj4);
    #pragma unroll
    for (int jj = 0; jj < 4; ++jj)
      acc[rg][jj] += wv[jj] * y[rg][jj];
  }
}

__global__ __launch_bounds__(256, 2) void kmech(
    const float* __restrict__ x, char* __restrict__ ws)
{
  __shared__ float wmT[32 * 68];   // [mm][row(64)+pad]
  const int tid = threadIdx.x;
  const int lane = tid & 63, wq = tid >> 6;
  const int b = blockIdx.x;
  const int tile = b >> 2, eh = (b >> 1) & 1, mh = b & 1;
  const int tb = tile * 64;
  const int lr = lane & 15, lg = lane >> 4;
  const int lk = lg * 8, lj4 = lg * 4;

  const char* wttc = (const char*)(ws + WS_WTT);
  const float* wT = (const float*)(ws + WS_WT);
  float* selOut = (float*)(ws + (mh ? WS_SEL1 : WS_SEL0));

  {  // w tile -> LDS transposed [mm][row]
    int mm = tid >> 3, r0 = (tid & 7) * 8;
    const float* src = wT + (mh * 32 + mm) * 8192 + tb + r0;
    float4 a = *(const float4*)src, c = *(const float4*)(src + 4);
    *(float4*)&wmT[mm * 68 + r0] = a;
    *(float4*)&wmT[mm * 68 + r0 + 4] = c;
  }
  bf16x8 aX[4][4];
  #pragma unroll
  for (int rg = 0; rg < 4; ++rg) {
    const float* xr = x + (tb + rg * 16 + lr) * 128;
    #pragma unroll
    for (int ks = 0; ks < 4; ++ks)
      aX[rg][ks] = cvt8(*(const float4*)(xr + ks * 32 + lk),
                        *(const float4*)(xr + ks * 32 + lk + 4));
  }
  f32x4 acc[4] = {{0,0,0,0},{0,0,0,0},{0,0,0,0},{0,0,0,0}};
  __syncthreads();

  const char* bbase = wttc + (size_t)(mh * 32) * 32768
                    + (size_t)(((eh * 64 + wq * 16 + lr) * 32 + lg * 8) * 2);
  bf16x8 F0[4], F1[4], F2[4], F3[4];
  loadF(F0, bbase, 0);
  loadF(F1, bbase, 1);
  loadF(F2, bbase, 2);

  #pragma unroll
  for (int it = 0; it < 8; ++it) {
    const int base = it * 4;
    const int n3 = base + 3;
    const int n4 = base + 4 > 31 ? 31 : base + 4;
    const int n5 = base + 5 > 31 ? 31 : base + 5;
    const int n6 = base + 6 > 31 ? 31 : base + 6;
    loadF(F3, bbase, n3);
    stepM(F0, &wmT[(base + 0) * 68], aX, acc, lj4);
    loadF(F0, bbase, n4);
    stepM(F1, &wmT[(base + 1) * 68], aX, acc, lj4);
    loadF(F1, bbase, n5);
    stepM(F2, &wmT[(base + 2) * 68], aX, acc, lj4);
    loadF(F2, bbase, n6);
    stepM(F3, &wmT[(base + 3) * 68], aX, acc, lj4);
  }

  #pragma unroll
  for (int rg = 0; rg < 4; ++rg)
    #pragma unroll
    for (int j = 0; j < 4; ++j)
      selOut[(tb + rg * 16 + lj4 + j) * 128 + eh * 64 + wq * 16 + lr] = acc[rg][j];
}

// ---------------------------------------------------------------- kernel D (integrate)
__global__ __launch_bounds__(256) void kinteg(
    const float* __restrict__ x, const float* __restrict__ bi,
    const char* __restrict__ ws, float* __restrict__ out)
{
  const int tid = threadIdx.x;
  const int lane = tid & 63, wq = tid >> 6;
  const int tb = blockIdx.x * 32;
  const int lr = lane & 15, lg = lane >> 4;
  const int lk = lg * 8, lj4 = lg * 4;
  const bf16_t* Wit = (const bf16_t*)(ws + WS_WIT);
  const float* s0 = (const float*)(ws + WS_SEL0);
  const float* s1 = (const float*)(ws + WS_SEL1);
  const float* sb = (const float*)(ws + WS_SBIAS);

  bf16x8 aF[2][8];
  #pragma unroll
  for (int rg = 0; rg < 2; ++rg) {
    int t = tb + rg * 16 + lr;
    #pragma unroll
    for (int ks = 0; ks < 4; ++ks) {
      const float* src = x + t * 128 + ks * 32 + lk;
      aF[rg][ks] = cvt8(*(const float4*)src, *(const float4*)(src + 4));
    }
    #pragma unroll
    for (int ks = 0; ks < 4; ++ks) {
      int idx = t * 128 + ks * 32 + lk;
      float4 a0 = *(const float4*)(s0 + idx);
      float4 a1 = *(const float4*)(s1 + idx);
      float4 a2 = *(const float4*)(sb + idx);
      float4 b0 = *(const float4*)(s0 + idx + 4);
      float4 b1 = *(const float4*)(s1 + idx + 4);
      float4 b2 = *(const float4*)(sb + idx + 4);
      float4 u; u.x = a0.x + a1.x + a2.x; u.y = a0.y + a1.y + a2.y;
      u.z = a0.z + a1.z + a2.z; u.w = a0.w + a1.w + a2.w;
      float4 v; v.x = b0.x + b1.x + b2.x; v.y = b0.y + b1.y + b2.y;
      v.z = b0.z + b1.z + b2.z; v.w = b0.w + b1.w + b2.w;
      aF[rg][4 + ks] = cvt8(u, v);
    }
  }
  #pragma unroll
  for (int cg = 0; cg < 2; ++cg) {
    int c = wq * 32 + cg * 16 + lr;
    f32x4 a0 = {0,0,0,0}, a1 = {0,0,0,0};
    #pragma unroll
    for (int ks = 0; ks < 8; ++ks) {
      bf16x8 b = *(const bf16x8*)(Wit + c * 256 + ks * 32 + lk);
      a0 = mfma16(aF[0][ks], b, a0);
      a1 = mfma16(aF[1][ks], b, a1);
    }
    float bb = bi[c];
    #pragma unroll
    for (int j = 0; j < 4; ++j) {
      out[(tb + lj4 + j) * 128 + c] = a0[j] + bb;
      out[(tb + 16 + lj4 + j) * 128 + c] = a1[j] + bb;
    }
  }
}

// ---------------------------------------------------------------- launch
extern "C" void kernel_launch(void* const* d_in, const int* in_sizes, int n_in,
                              void* d_out, int out_size, void* d_ws, size_t ws_size,
                              hipStream_t stream)
{
  (void)in_sizes; (void)n_in; (void)out_size; (void)ws_size;
  const float* x   = (const float*)d_in[0];
  const float* ctx = (const float*)d_in[1];
  const float* Wt  = (const float*)d_in[2];
  const float* bt  = (const float*)d_in[3];
  const float* ch  = (const float*)d_in[4];
  const float* Wg  = (const float*)d_in[5];
  const float* bg  = (const float*)d_in[6];
  const float* Wv  = (const float*)d_in[7];
  const float* bv  = (const float*)d_in[8];
  const float* O   = (const float*)d_in[9];
  const float* W1  = (const float*)d_in[10];
  const float* b1  = (const float*)d_in[11];
  const float* W2  = (const float*)d_in[12];
  const float* b2  = (const float*)d_in[13];
  const float* Wi  = (const float*)d_in[14];
  const float* bi  = (const float*)d_in[15];
  float* out = (float*)d_out;
  char* ws = (char*)d_ws;

  kprep<<<186, 256, 0, stream>>>(Wt, bt, ch, Wg, Wv, bv, O, W1, W2, Wi, ws);
  kselect<<<256, 256, 0, stream>>>(x, ctx, b1, b2, bg, ws, out);
  kmech<<<512, 256, 0, stream>>>(x, ws);
  kinteg<<<256, 256, 0, stream>>>(x, bi, ws, out);
}